// Round 13
// baseline (383.902 us; speedup 1.0000x reference)
//
#include <hip/hip_runtime.h>
#include <math.h>

#define Bsz 4
#define Cch 32
#define Hh 48
#define Ww 48
#define HWsz 2304          // 48*48
#define BHW 9216           // 4*2304
#define CIN_CAT 96
#define NSPLIT 32          // column splits for max partials (8 per b-group)
#define TILES_PER_SPLIT 18 // 576 col-tiles / 32 (18 | 144 -> split stays in one b)

typedef __bf16 bf16_t;
typedef __bf16 bf16x8 __attribute__((ext_vector_type(8)));
typedef float f32x4 __attribute__((ext_vector_type(4)));

// ---------------- bilinear resize, align_corners=True ----------------
__global__ void resize_kernel(const float* __restrict__ in, float* __restrict__ out,
                              int inH, int inW, int rowStride, int chanStride, int baseOff,
                              float scaleY, float scaleX, int outCtot, int chanOff) {
    int idx = blockIdx.x * blockDim.x + threadIdx.x;
    if (idx >= Bsz * Cch * HWsz) return;
    int x = idx % Ww;
    int y = (idx / Ww) % Hh;
    int c = (idx / HWsz) % Cch;
    int b = idx / (HWsz * Cch);
    float fy = y * scaleY;
    float fx = x * scaleX;
    int y0 = (int)floorf(fy); int x0 = (int)floorf(fx);
    y0 = min(y0, inH - 1); x0 = min(x0, inW - 1);
    int y1 = min(y0 + 1, inH - 1); int x1 = min(x0 + 1, inW - 1);
    float wy = fy - (float)y0, wx = fx - (float)x0;
    const float* src = in + (size_t)(b * Cch + c) * chanStride + baseOff;
    float v00 = src[y0 * rowStride + x0];
    float v01 = src[y0 * rowStride + x1];
    float v10 = src[y1 * rowStride + x0];
    float v11 = src[y1 * rowStride + x1];
    float top = v00 * (1.f - wx) + v01 * wx;
    float bot = v10 * (1.f - wx) + v11 * wx;
    float r = top * (1.f - wy) + bot * wy;
    out[((size_t)(b * outCtot) + c + chanOff) * HWsz + y * Ww + x] = r;
}

// copy x1 (B,32,HW) into cat channels [64..96)
__global__ void copy_x1_kernel(const float* __restrict__ x1, float* __restrict__ cat) {
    int idx = blockIdx.x * blockDim.x + threadIdx.x;
    if (idx >= Bsz * Cch * HWsz) return;
    int hw = idx % HWsz;
    int c = (idx / HWsz) % Cch;
    int b = idx / (HWsz * Cch);
    cat[((size_t)(b * CIN_CAT) + 64 + c) * HWsz + hw] = x1[idx];
}

// ---------------- conv prep: activations [b][ci][hw] -> [p][ci] split-bf16 --------
// LDS tile transpose: coalesced hw-major reads, padded LDS, coalesced ci-major writes.
// grid BHW/64 = 144 blocks x 256 threads.
template<int CIN, bool HAS2>
__global__ void prep_x_t_kernel(const float* __restrict__ X, const float* __restrict__ X2,
                                bf16_t* __restrict__ xhi, bf16_t* __restrict__ xlo) {
    __shared__ float lds[CIN][65];     // +1 pad: transpose-read conflict-free
    int p0 = blockIdx.x * 64;          // 64 | HWsz -> block stays within one b
    int b  = p0 / HWsz;
    int hw0 = p0 % HWsz;
    int tid = threadIdx.x;
    for (int i = tid; i < CIN * 64; i += 256) {
        int hwl = i % 64;              // lane-fast -> coalesced global read
        int ci  = i / 64;
        size_t gi = ((size_t)(b * CIN) + ci) * HWsz + hw0 + hwl;
        float v = X[gi];
        if (HAS2) v += X2[gi];
        lds[ci][hwl] = v;
    }
    __syncthreads();
    for (int i = tid; i < CIN * 64; i += 256) {
        int ci = i % CIN;              // lane-fast -> coalesced bf16 write
        int pl = i / CIN;
        float v = lds[ci][pl];
        bf16_t h = (bf16_t)v;
        size_t oi = (size_t)(p0 + pl) * CIN + ci;
        xhi[oi] = h;
        xlo[oi] = (bf16_t)(v - (float)h);
    }
}

// ---------------- conv prep: weights [co][ci][3][3] -> [tap][co32][ci] split-bf16 --
// also zero-fills zbuf (fused former zeros_kernel)
__global__ void prep_w_kernel(const float* __restrict__ w, int Cout, int CINr,
                              bf16_t* __restrict__ whi, bf16_t* __restrict__ wlo,
                              bf16_t* __restrict__ zbuf) {
    int idx = blockIdx.x * 256 + threadIdx.x;
    if (idx < 128) zbuf[idx] = (bf16_t)0.f;
    if (idx >= 9 * 32 * CINr) return;
    int ci = idx % CINr;
    int rem = idx / CINr;
    int co = rem % 32;
    int tap = rem / 32;
    float v = (co < Cout) ? w[((size_t)(co * CINr) + ci) * 9 + tap] : 0.f;
    bf16_t h = (bf16_t)v;
    whi[idx] = h;
    wlo[idx] = (bf16_t)(v - (float)h);
}

// ---------------- 3x3 conv as implicit GEMM on MFMA, fused BN (+residual) ---------
template<int CIN, int COUT_WRITE, bool HASRES>
__global__ __launch_bounds__(256) void conv_mfma_kernel(
        const bf16_t* __restrict__ xhi, const bf16_t* __restrict__ xlo,
        const bf16_t* __restrict__ whi, const bf16_t* __restrict__ wlo,
        const bf16_t* __restrict__ zbuf,
        const float* __restrict__ bng, const float* __restrict__ bnb,
        const float* __restrict__ res, float* __restrict__ out) {
    int lane = threadIdx.x & 63;
    int mt = blockIdx.x * 4 + (threadIdx.x >> 6);   // 0..575
    int lrow = lane & 15;
    int lk = lane >> 4;
    int p = mt * 16 + lrow;
    int hw = p % HWsz;
    int y = hw / Ww, x = hw % Ww;
    f32x4 acc0 = {0.f, 0.f, 0.f, 0.f};
    f32x4 acc1 = {0.f, 0.f, 0.f, 0.f};
#pragma unroll
    for (int tap = 0; tap < 9; ++tap) {
        const int dy = tap / 3 - 1, dx = tap % 3 - 1;
        bool valid = ((unsigned)(y + dy) < (unsigned)Hh) && ((unsigned)(x + dx) < (unsigned)Ww);
        const bf16_t* ah = valid ? xhi + (size_t)(p + dy * Ww + dx) * CIN : zbuf;
        const bf16_t* al = valid ? xlo + (size_t)(p + dy * Ww + dx) * CIN : zbuf;
#pragma unroll
        for (int c = 0; c < CIN / 32; ++c) {
            bf16x8 ahi = *(const bf16x8*)(ah + c * 32 + lk * 8);
            bf16x8 alo = *(const bf16x8*)(al + c * 32 + lk * 8);
            size_t w0 = (size_t)(tap * 32 + lrow) * CIN + c * 32 + lk * 8;
            size_t w1 = (size_t)(tap * 32 + 16 + lrow) * CIN + c * 32 + lk * 8;
            bf16x8 bhi0 = *(const bf16x8*)(whi + w0);
            bf16x8 blo0 = *(const bf16x8*)(wlo + w0);
            bf16x8 bhi1 = *(const bf16x8*)(whi + w1);
            bf16x8 blo1 = *(const bf16x8*)(wlo + w1);
            acc0 = __builtin_amdgcn_mfma_f32_16x16x32_bf16(ahi, bhi0, acc0, 0, 0, 0);
            acc0 = __builtin_amdgcn_mfma_f32_16x16x32_bf16(ahi, blo0, acc0, 0, 0, 0);
            acc0 = __builtin_amdgcn_mfma_f32_16x16x32_bf16(alo, bhi0, acc0, 0, 0, 0);
            acc1 = __builtin_amdgcn_mfma_f32_16x16x32_bf16(ahi, bhi1, acc1, 0, 0, 0);
            acc1 = __builtin_amdgcn_mfma_f32_16x16x32_bf16(ahi, blo1, acc1, 0, 0, 0);
            acc1 = __builtin_amdgcn_mfma_f32_16x16x32_bf16(alo, bhi1, acc1, 0, 0, 0);
        }
    }
    float bsc = rsqrtf(1.0f + 1e-5f);
    int co0 = lrow, co1 = 16 + lrow;
    float s0, b0, s1 = 0.f, b1 = 0.f;
    if (COUT_WRITE == 32) {
        s0 = bng[co0] * bsc; b0 = bnb[co0];
        s1 = bng[co1] * bsc; b1 = bnb[co1];
    } else {
        s0 = bng[0] * bsc; b0 = bnb[0];
    }
    // C/D layout: col = lane&15 (= co within tile), row = (lane>>4)*4 + r (= pixel)
#pragma unroll
    for (int r = 0; r < 4; ++r) {
        int pr = mt * 16 + lk * 4 + r;
        int br = pr / HWsz, hwr = pr % HWsz;
        if (COUT_WRITE == 32) {
            size_t o0 = ((size_t)(br * 32) + co0) * HWsz + hwr;
            float v0 = acc0[r] * s0 + b0;
            if (HASRES) v0 += res[o0];
            out[o0] = v0;
            size_t o1 = ((size_t)(br * 32) + co1) * HWsz + hwr;
            float v1 = acc1[r] * s1 + b1;
            if (HASRES) v1 += res[o1];
            out[o1] = v1;
        } else {
            if (lrow == 0) out[(size_t)br * HWsz + hwr] = acc0[r] * s0 + b0;
        }
    }
}

// ---------------- SA: fused 1x1 convs for q, k, c(no-bias) ----------------
__global__ void qkc_kernel(const float* __restrict__ x,
                           const float* __restrict__ qw, const float* __restrict__ qb,
                           const float* __restrict__ kw, const float* __restrict__ kb,
                           const float* __restrict__ cw,
                           float* __restrict__ qbuf, float* __restrict__ kT,
                           float* __restrict__ cnb,
                           bf16_t* __restrict__ qhi, bf16_t* __restrict__ qlo,
                           bf16_t* __restrict__ khi, bf16_t* __restrict__ klo) {
    int p = blockIdx.x * blockDim.x + threadIdx.x;  // pixel 0..9215
    if (p >= BHW) return;
    int b = p / HWsz;
    int hw = p % HWsz;
    float xin[Cch];
#pragma unroll
    for (int ci = 0; ci < Cch; ++ci) xin[ci] = x[((size_t)(b * Cch) + ci) * HWsz + hw];
    int which = blockIdx.y;
    if (which == 0) {
        for (int co = 0; co < Cch; ++co) {
            float acc = qb[co];
#pragma unroll
            for (int ci = 0; ci < Cch; ++ci) acc += xin[ci] * qw[co * Cch + ci];
            size_t f = ((size_t)(b * Cch) + co) * HWsz + hw;
            qbuf[f] = acc;
            bf16_t h = (bf16_t)acc;
            qhi[f] = h;
            qlo[f] = (bf16_t)(acc - (float)h);
        }
    } else if (which == 1) {
        for (int co = 0; co < Cch; ++co) {
            float acc = kb[co];
#pragma unroll
            for (int ci = 0; ci < Cch; ++ci) acc += xin[ci] * kw[co * Cch + ci];
            size_t f = (size_t)p * Cch + co;
            kT[f] = acc;
            bf16_t h = (bf16_t)acc;
            khi[f] = h;
            klo[f] = (bf16_t)(acc - (float)h);
        }
    } else {
        for (int co = 0; co < Cch; ++co) {
            float acc = 0.f;
#pragma unroll
            for (int ci = 0; ci < Cch; ++ci) acc += xin[ci] * cw[co * Cch + ci];
            cnb[((size_t)(b * Cch) + co) * HWsz + hw] = acc;
        }
    }
}

// ---------------- ksum: column sums of kT (exact fp32, for the mean term) ----------
__global__ void ksum_kernel(const float* __restrict__ kT, float* __restrict__ ksum) {
    int c = blockIdx.x;   // 0..31
    int tid = threadIdx.x;
    __shared__ float red[256];
    float s = 0.f;
    for (int j = tid; j < BHW; j += 256) s += kT[(size_t)j * Cch + c];
    red[tid] = s; __syncthreads();
    for (int st = 128; st > 0; st >>= 1) { if (tid < st) red[tid] += red[tid + st]; __syncthreads(); }
    if (tid == 0) ksum[c] = red[0];
}

// ---------------- score max-scan via MFMA (split-bf16: hi*hi + hi*lo + lo*hi) -------
// 8 row-tiles per wave: B fragments loaded once feed 8 independent MFMA chains
// (B L2-traffic halved vs 4-tile; 8-way MFMA ILP). grid (18, NSPLIT) x 256 threads.
__global__ void score_mfma_kernel(const bf16_t* __restrict__ qhi, const bf16_t* __restrict__ qlo,
                                  const bf16_t* __restrict__ khi, const bf16_t* __restrict__ klo,
                                  float* __restrict__ pmax) {
    int wave = threadIdx.x >> 6;
    int lane = threadIdx.x & 63;
    int gw = blockIdx.x * 4 + wave;   // 0..71, owns row-tiles gw*8 .. gw*8+7
    int cs = blockIdx.y;              // 0..31
    int lrow = lane & 15;
    int lk = lane >> 4;
    bf16x8 ahi[8], alo[8];
#pragma unroll
    for (int j = 0; j < 8; ++j) {
        size_t aoff = (size_t)((gw * 8 + j) * 16 + lrow) * Cch + lk * 8;
        ahi[j] = *(const bf16x8*)(qhi + aoff);
        alo[j] = *(const bf16x8*)(qlo + aoff);
    }
    f32x4 mx[8];
#pragma unroll
    for (int j = 0; j < 8; ++j) { mx[j][0] = -1e30f; mx[j][1] = -1e30f; mx[j][2] = -1e30f; mx[j][3] = -1e30f; }
    int ct0 = cs * TILES_PER_SPLIT;
    for (int ct = ct0; ct < ct0 + TILES_PER_SPLIT; ++ct) {
        size_t boff = (size_t)(ct * 16 + lrow) * Cch + lk * 8;
        bf16x8 bhi = *(const bf16x8*)(khi + boff);
        bf16x8 blo = *(const bf16x8*)(klo + boff);
#pragma unroll
        for (int j = 0; j < 8; ++j) {
            f32x4 d = {0.f, 0.f, 0.f, 0.f};
            d = __builtin_amdgcn_mfma_f32_16x16x32_bf16(ahi[j], bhi, d, 0, 0, 0);
            d = __builtin_amdgcn_mfma_f32_16x16x32_bf16(ahi[j], blo, d, 0, 0, 0);
            d = __builtin_amdgcn_mfma_f32_16x16x32_bf16(alo[j], bhi, d, 0, 0, 0);
#pragma unroll
            for (int r = 0; r < 4; ++r) mx[j][r] = fmaxf(mx[j][r], d[r]);
        }
    }
    // reduce max across the 16 column-lanes of each row group
#pragma unroll
    for (int off = 1; off < 16; off <<= 1) {
#pragma unroll
        for (int j = 0; j < 8; ++j) {
#pragma unroll
            for (int r = 0; r < 4; ++r) {
                float o = __shfl_xor(mx[j][r], off, 64);
                mx[j][r] = fmaxf(mx[j][r], o);
            }
        }
    }
    if (lrow == 0) {
#pragma unroll
        for (int j = 0; j < 8; ++j) {
#pragma unroll
            for (int r = 0; r < 4; ++r) {
                int row = (gw * 8 + j) * 16 + lk * 4 + r;   // C/D layout: row=(lane>>4)*4+reg
                pmax[(size_t)cs * BHW + row] = mx[j][r];
            }
        }
    }
}

// ---------------- logits: mean_b(max) + q.ksum/BHW, scaled ----------------
__global__ void logits_kernel(const float* __restrict__ qbuf, const float* __restrict__ ksum,
                              const float* __restrict__ pmax, float* __restrict__ logits) {
    __shared__ float ks[Cch];
    if (threadIdx.x < Cch) ks[threadIdx.x] = ksum[threadIdx.x];
    __syncthreads();
    int i = blockIdx.x * 256 + threadIdx.x;
    if (i >= BHW) return;
    float msum = 0.f;
#pragma unroll
    for (int b = 0; b < 4; ++b) {
        float m = -1e30f;
#pragma unroll
        for (int k = 0; k < 8; ++k) m = fmaxf(m, pmax[(size_t)(b * 8 + k) * BHW + i]);
        msum += m;
    }
    float dot = 0.f;
    const float4* qp = (const float4*)(qbuf + (size_t)i * Cch);
#pragma unroll
    for (int t = 0; t < 8; ++t) {
        float4 v = qp[t];
        dot += v.x * ks[4 * t] + v.y * ks[4 * t + 1] + v.z * ks[4 * t + 2] + v.w * ks[4 * t + 3];
    }
    logits[i] = (msum * 0.25f + dot * (1.0f / (float)BHW)) * 0.17677669529663687f;
}

// softmax over HW per b -> xco
__global__ void softmax_kernel(const float* __restrict__ logits, float* __restrict__ xco) {
    int b = blockIdx.x;
    int tid = threadIdx.x;
    __shared__ float red[256];
    const float* l = logits + (size_t)b * HWsz;
    float m = -1e30f;
    for (int h = tid; h < HWsz; h += 256) m = fmaxf(m, l[h]);
    red[tid] = m; __syncthreads();
    for (int s = 128; s > 0; s >>= 1) { if (tid < s) red[tid] = fmaxf(red[tid], red[tid + s]); __syncthreads(); }
    m = red[0]; __syncthreads();
    float s = 0.f;
    for (int h = tid; h < HWsz; h += 256) s += expf(l[h] - m);
    red[tid] = s; __syncthreads();
    for (int st = 128; st > 0; st >>= 1) { if (tid < st) red[tid] += red[tid + st]; __syncthreads(); }
    float inv = 1.0f / red[0];
    for (int h = tid; h < HWsz; h += 256) xco[(size_t)b * HWsz + h] = expf(l[h] - m) * inv;
}

// out[b,c,hw] = cnb[b,c,hw] * xco[b,hw] + cb[c]
__global__ void sa_apply_kernel(const float* __restrict__ cnb, const float* __restrict__ xco,
                                const float* __restrict__ cb, float* __restrict__ out) {
    int idx = blockIdx.x * blockDim.x + threadIdx.x;
    if (idx >= Bsz * Cch * HWsz) return;
    int hw = idx % HWsz;
    int c = (idx / HWsz) % Cch;
    int b = idx / (HWsz * Cch);
    out[idx] = cnb[idx] * xco[(size_t)b * HWsz + hw] + cb[c];
}

extern "C" void kernel_launch(void* const* d_in, const int* in_sizes, int n_in,
                              void* d_out, int out_size, void* d_ws, size_t ws_size,
                              hipStream_t stream) {
    const float* x1      = (const float*)d_in[0];
    const float* x2      = (const float*)d_in[1];
    const float* x3      = (const float*)d_in[2];
    const float* conv1_w = (const float*)d_in[3];
    const float* bn1_g   = (const float*)d_in[4];
    const float* bn1_b   = (const float*)d_in[5];
    const float* conv4_w = (const float*)d_in[6];
    const float* bn4_g   = (const float*)d_in[7];
    const float* bn4_b   = (const float*)d_in[8];
    const float* conv5_w = (const float*)d_in[9];
    const float* bn5_g   = (const float*)d_in[10];
    const float* bn5_b   = (const float*)d_in[11];
    const float* convfs_w= (const float*)d_in[12];
    const float* bnfs_g  = (const float*)d_in[13];
    const float* bnfs_b  = (const float*)d_in[14];
    const float* saq_w   = (const float*)d_in[15];
    const float* saq_b   = (const float*)d_in[16];
    const float* sak_w   = (const float*)d_in[17];
    const float* sak_b   = (const float*)d_in[18];
    const float* sac6_w  = (const float*)d_in[19];
    const float* sac6_b  = (const float*)d_in[20];

    float* ws = (float*)d_ws;
    const size_t TEN = (size_t)Bsz * Cch * HWsz;  // 294912
    // ---- persistent region (~11.9 MB) ----
    float* cat    = ws;                            // B*96*HW
    float* f1     = cat + (size_t)Bsz * CIN_CAT * HWsz;
    float* f_s_1  = f1 + TEN;
    float* fg     = f_s_1 + TEN;
    float* fs     = fg + TEN;
    float* sfs    = fs + TEN;
    float* fgl    = sfs + TEN;
    float* t1     = fgl + TEN;
    float* logits = t1 + TEN;              // 9216
    float* xco    = logits + BHW;          // 9216
    float* ksum   = xco + BHW;             // 64 floats reserved
    // ---- shared arena: SA-scratch and conv-scratch never live simultaneously ----
    float* arena  = ksum + 64;
    // SA view (live only inside run_sa): 3*TEN f32 + 32*BHW f32 + 4*TEN bf16 ≈ 7.1 MB
    float* qbuf   = arena;
    float* kT     = qbuf + TEN;
    float* cnb    = kT + TEN;
    float* pmax   = cnb + TEN;                       // 32*9216
    bf16_t* qhi   = (bf16_t*)(pmax + (size_t)NSPLIT * BHW);
    bf16_t* qlo   = qhi + TEN;
    bf16_t* khi   = qlo + TEN;
    bf16_t* klo   = khi + TEN;
    // conv view (live only around conv calls): ≈ 3.7 MB, aliases the SA view
    bf16_t* xthi  = (bf16_t*)arena;                  // BHW*96
    bf16_t* xtlo  = xthi + (size_t)BHW * CIN_CAT;
    bf16_t* wthi  = xtlo + (size_t)BHW * CIN_CAT;    // 9*32*96
    bf16_t* wtlo  = wthi + 9 * 32 * CIN_CAT;
    bf16_t* zbuf  = wtlo + 9 * 32 * CIN_CAT;         // 128 zeros

    const int TPB = 256;
    const int GRID_TEN = (int)((TEN + TPB - 1) / TPB);   // 1152
    const int GRID_MFMA = 144;                            // 576 waves
    const int GRID_PREP = BHW / 64;                       // 144

    // 1. f3 = resize(x3, 192->48) into cat ch[0:32)
    resize_kernel<<<GRID_TEN, TPB, 0, stream>>>(x3, cat, 192, 192, 192, 192 * 192, 0,
                                                191.0f / 47.0f, 191.0f / 47.0f, CIN_CAT, 0);
    // 2. f2 = resize(x2, 96->48) into cat ch[32:64)
    resize_kernel<<<GRID_TEN, TPB, 0, stream>>>(x2, cat, 96, 96, 96, 96 * 96, 0,
                                                95.0f / 47.0f, 95.0f / 47.0f, CIN_CAT, 32);
    // 3. x1 into cat ch[64:96)
    copy_x1_kernel<<<GRID_TEN, TPB, 0, stream>>>(x1, cat);
    // 4. f1 = bn1(conv1(cat))  via implicit-GEMM MFMA
    prep_w_kernel<<<(9 * 32 * CIN_CAT + 255) / 256, 256, 0, stream>>>(conv1_w, 32, CIN_CAT, wthi, wtlo, zbuf);
    prep_x_t_kernel<CIN_CAT, false><<<GRID_PREP, 256, 0, stream>>>(cat, nullptr, xthi, xtlo);
    conv_mfma_kernel<CIN_CAT, 32, false><<<GRID_MFMA, 256, 0, stream>>>(
        xthi, xtlo, wthi, wtlo, zbuf, bn1_g, bn1_b, nullptr, f1);
    // 5. f_s_1 = resize(f1[:, :, 32:48, 32:48], 16->48)  (chunk idx is always 8)
    resize_kernel<<<GRID_TEN, TPB, 0, stream>>>(f1, f_s_1, 16, 16, Ww, HWsz, 32 * Ww + 32,
                                                15.0f / 47.0f, 15.0f / 47.0f, Cch, 0);

    // SA macro: x -> out
    auto run_sa = [&](const float* xin, float* outp) {
        dim3 g1((BHW + TPB - 1) / TPB, 3);
        qkc_kernel<<<g1, TPB, 0, stream>>>(xin, saq_w, saq_b, sak_w, sak_b, sac6_w,
                                           qbuf, kT, cnb, qhi, qlo, khi, klo);
        ksum_kernel<<<Cch, 256, 0, stream>>>(kT, ksum);
        dim3 g2(18, NSPLIT);
        score_mfma_kernel<<<g2, 256, 0, stream>>>(qhi, qlo, khi, klo, pmax);
        logits_kernel<<<BHW / 256, 256, 0, stream>>>(qbuf, ksum, pmax, logits);
        softmax_kernel<<<Bsz, 256, 0, stream>>>(logits, xco);
        sa_apply_kernel<<<GRID_TEN, TPB, 0, stream>>>(cnb, xco, sac6_b, outp);
    };

    // 6-8. fg = sa(f1); fs = sa(f_s_1); sfs = sa(fs)
    run_sa(f1, fg);
    run_sa(f_s_1, fs);
    run_sa(fs, sfs);

    // 9. fgl = bnfs(convfs(fg + sfs))
    prep_w_kernel<<<(9 * 32 * Cch + 255) / 256, 256, 0, stream>>>(convfs_w, 32, Cch, wthi, wtlo, zbuf);
    prep_x_t_kernel<Cch, true><<<GRID_PREP, 256, 0, stream>>>(fg, sfs, xthi, xtlo);
    conv_mfma_kernel<Cch, 32, false><<<GRID_MFMA, 256, 0, stream>>>(
        xthi, xtlo, wthi, wtlo, zbuf, bnfs_g, bnfs_b, nullptr, fgl);
    // 10. t1 = bn4(conv4(fgl)) + fg
    prep_w_kernel<<<(9 * 32 * Cch + 255) / 256, 256, 0, stream>>>(conv4_w, 32, Cch, wthi, wtlo, zbuf);
    prep_x_t_kernel<Cch, false><<<GRID_PREP, 256, 0, stream>>>(fgl, nullptr, xthi, xtlo);
    conv_mfma_kernel<Cch, 32, true><<<GRID_MFMA, 256, 0, stream>>>(
        xthi, xtlo, wthi, wtlo, zbuf, bn4_g, bn4_b, fg, t1);
    // 11. out = bn5(conv5(t1))   (B,1,48,48)
    prep_w_kernel<<<(9 * 32 * Cch + 255) / 256, 256, 0, stream>>>(conv5_w, 1, Cch, wthi, wtlo, zbuf);
    prep_x_t_kernel<Cch, false><<<GRID_PREP, 256, 0, stream>>>(t1, nullptr, xthi, xtlo);
    conv_mfma_kernel<Cch, 1, false><<<GRID_MFMA, 256, 0, stream>>>(
        xthi, xtlo, wthi, wtlo, zbuf, bn5_g, bn5_b, nullptr, (float*)d_out);
}